// Round 3
// baseline (448.538 us; speedup 1.0000x reference)
//
#include <hip/hip_runtime.h>
#include <hip/hip_bf16.h>

// ---------------------------------------------------------------------------
// TensorProductLinearGate: fused CG tensor product + block linear + gate.
// N=65536 nodes, MUL=128.
//   s    = tp0 @ W0 /16 + b0            (tp0 = [x0*y0 ; dot(x1,y1)/sqrt3], K=256)
//   v1o  = (y1[i]*p0 + y0*p1[i]) /16    (p0 = x0@W1o_top, p1i = x1i@W1o_bot)
//   v1e  = (y1[i2]*q[i1]-y1[i1]*q[i2])/16   (q_i = x1i@W1e ; /sqrt2/sqrt128 = /16)
//   out  = [silu(s[256:]) | v1o*sig(s[0:128]) | v1e*sig(s[128:256])]
// bf16 MFMA 16x16x32, fp32 accum. Weights pre-transposed to [out][K] bf16 in ws.
// Round 3: OPERAND-SWAPPED MFMA -> D[o][node] so each lane owns 4 consecutive
// output channels of ONE node => all stores are aligned float4 (was 28 scattered
// dwords/thread -> 14 dwordx4/thread). Round-2 counters showed store-path bound
// (1.2 TB/s write, MfmaUtil 5.9%).
// ---------------------------------------------------------------------------

typedef __bf16 bf16x8 __attribute__((ext_vector_type(8)));
typedef float f32x4 __attribute__((ext_vector_type(4)));
typedef unsigned short u16x8 __attribute__((ext_vector_type(8)));

#define W1OT_TOP 98304
#define W1OT_BOT 114688
#define W1ET     131072
#define INV16 0.0625f
#define INV_SQRT3 0.57735026918962576f

__device__ __forceinline__ unsigned short f2bf(float f) {
    unsigned u = __float_as_uint(f);
    u += 0x7FFFu + ((u >> 16) & 1u);
    return (unsigned short)(u >> 16);
}

// ---- weight prep: f32 [K][out] -> bf16 [out][K] (transposed), into ws ----
__global__ __launch_bounds__(256) void prep_w(const float* __restrict__ W0,
                                              const float* __restrict__ W1o,
                                              const float* __restrict__ W1e,
                                              unsigned short* __restrict__ ws) {
    int idx = blockIdx.x * 256 + threadIdx.x;   // grid covers exactly 147456
    float v;
    if (idx < 98304) {                 // W0T[o][k], o<384, k<256
        int o = idx >> 8, k = idx & 255;
        v = W0[k * 384 + o];
    } else if (idx < 114688) {         // W1o top half: k<128
        int j = idx - 98304; int o = j >> 7, k = j & 127;
        v = W1o[k * 128 + o];
    } else if (idx < 131072) {         // W1o bottom half: k in [128,256)
        int j = idx - 114688; int o = j >> 7, k = j & 127;
        v = W1o[(128 + k) * 128 + o];
    } else {                           // W1e
        int j = idx - 131072; int o = j >> 7, k = j & 127;
        v = W1e[k * 128 + o];
    }
    ws[idx] = f2bf(v);
}

// LDS layout (ushort units):
//   [0,2048)      x0sm   [16][128]
//   [2048,8192)   x1sm   [3][16][128]
//   [8192,12288)  tp0sm  [16][256]
// all rows XOR-swizzled by ((row&7)*8) on the 8-element-chunk index.
__global__ __launch_bounds__(256, 3) void tpl_gate(
    const float* __restrict__ x0, const float* __restrict__ x1,
    const float* __restrict__ y0, const float* __restrict__ y1,
    const float* __restrict__ b0, const unsigned short* __restrict__ ws,
    float* __restrict__ out) {
    __shared__ alignas(16) unsigned short sm[12288];
    __shared__ alignas(16) float ysm[64];      // [16 nodes][y0,y1x,y1y,y1z]
    __shared__ alignas(16) float b0sm[384];

    const int t = threadIdx.x;
    const int base = blockIdx.x * 16;

    // ----------------- staging: global f32 -> LDS bf16 -----------------
    {
        const int r = t >> 4, cg = t & 15, c0 = cg * 8;
        const int n = base + r;
        const int swz = (r & 7) * 8;
        const float w0v = y0[n];
        const float w1x = y1[n * 3 + 0], w1y = y1[n * 3 + 1], w1z = y1[n * 3 + 2];

        // x0 chunk + tp0 top (x0*y0)
        const float4* px = (const float4*)(x0 + (size_t)n * 128 + c0);
        float4 a4 = px[0], b4 = px[1];
        float xa[8] = {a4.x, a4.y, a4.z, a4.w, b4.x, b4.y, b4.z, b4.w};
        u16x8 q0, q1;
#pragma unroll
        for (int e = 0; e < 8; e++) { q0[e] = f2bf(xa[e]); q1[e] = f2bf(xa[e] * w0v); }
        *(u16x8*)(&sm[r * 128 + (c0 ^ swz)]) = q0;
        *(u16x8*)(&sm[8192 + r * 256 + (c0 ^ swz)]) = q1;

        // x1 chunk (3 components) + tp0 bottom (dot(x1,y1)/sqrt3)
        const float4* p1 = (const float4*)(x1 + (size_t)n * 384 + c0 * 3);
        float xb[24];
#pragma unroll
        for (int e = 0; e < 6; e++) {
            float4 v = p1[e];
            xb[e * 4 + 0] = v.x; xb[e * 4 + 1] = v.y; xb[e * 4 + 2] = v.z; xb[e * 4 + 3] = v.w;
        }
        u16x8 qx, qy, qz, qt;
#pragma unroll
        for (int e = 0; e < 8; e++) {
            float vx = xb[e * 3 + 0], vy = xb[e * 3 + 1], vz = xb[e * 3 + 2];
            qx[e] = f2bf(vx); qy[e] = f2bf(vy); qz[e] = f2bf(vz);
            qt[e] = f2bf((vx * w1x + vy * w1y + vz * w1z) * INV_SQRT3);
        }
        *(u16x8*)(&sm[2048 + r * 128 + (c0 ^ swz)]) = qx;
        *(u16x8*)(&sm[4096 + r * 128 + (c0 ^ swz)]) = qy;
        *(u16x8*)(&sm[6144 + r * 128 + (c0 ^ swz)]) = qz;
        *(u16x8*)(&sm[8192 + r * 256 + ((128 + c0) ^ swz)]) = qt;

        if (t < 16) {
            int nn = base + t;
            ysm[t * 4 + 0] = y0[nn];
            ysm[t * 4 + 1] = y1[nn * 3 + 0];
            ysm[t * 4 + 2] = y1[nn * 3 + 1];
            ysm[t * 4 + 3] = y1[nn * 3 + 2];
        }
        if (t < 96) ((float4*)b0sm)[t] = ((const float4*)b0)[t];
    }
    __syncthreads();

    // ----------------- MFMA phase (operand-swapped: D[o][node]) -----------------
    const int wave = t >> 6, lane = t & 63;
    const int cl = lane & 15, g4 = lane >> 4;
    const int swzr = (cl & 7) * 8;
    const int o0A = wave * 16;        // o-tile pair: rows o0A.. and o0A+64..
    const int o0B = wave * 16 + 64;

    f32x4 accS[2][3], accP0[2], accP1[2][3], accQ[2][3];
#pragma unroll
    for (int p = 0; p < 2; p++) {
        accP0[p] = (f32x4)(0.0f);
#pragma unroll
        for (int g = 0; g < 3; g++) accS[p][g] = (f32x4)(0.0f);
#pragma unroll
        for (int i = 0; i < 3; i++) { accP1[p][i] = (f32x4)(0.0f); accQ[p][i] = (f32x4)(0.0f); }
    }
    const int oo[2] = {o0A, o0B};

    // s-path: tp0 (K=256) x W0T   — weights as A-operand, tp as B-operand
#pragma unroll
    for (int ks = 0; ks < 8; ks++) {
        int eb = ks * 32 + g4 * 8;
        bf16x8 a = *(const bf16x8*)(&sm[8192 + cl * 256 + (eb ^ swzr)]);
#pragma unroll
        for (int p = 0; p < 2; p++) {
#pragma unroll
            for (int g = 0; g < 3; g++) {
                int row = g * 128 + oo[p] + cl;
                bf16x8 b = *(const bf16x8*)(&ws[row * 256 + eb]);
                accS[p][g] = __builtin_amdgcn_mfma_f32_16x16x32_bf16(b, a, accS[p][g], 0, 0, 0);
            }
        }
    }
    // v-path: x0/x1 (K=128) x {W1o_top, W1o_bot, W1e}
#pragma unroll
    for (int k = 0; k < 4; k++) {
        int eb = k * 32 + g4 * 8;
        bf16x8 a0 = *(const bf16x8*)(&sm[0    + cl * 128 + (eb ^ swzr)]);
        bf16x8 ax = *(const bf16x8*)(&sm[2048 + cl * 128 + (eb ^ swzr)]);
        bf16x8 ay = *(const bf16x8*)(&sm[4096 + cl * 128 + (eb ^ swzr)]);
        bf16x8 az = *(const bf16x8*)(&sm[6144 + cl * 128 + (eb ^ swzr)]);
#pragma unroll
        for (int p = 0; p < 2; p++) {
            int row = oo[p] + cl;
            bf16x8 bt = *(const bf16x8*)(&ws[W1OT_TOP + row * 128 + eb]);
            bf16x8 bb = *(const bf16x8*)(&ws[W1OT_BOT + row * 128 + eb]);
            bf16x8 be = *(const bf16x8*)(&ws[W1ET     + row * 128 + eb]);
            accP0[p]    = __builtin_amdgcn_mfma_f32_16x16x32_bf16(bt, a0, accP0[p], 0, 0, 0);
            accP1[p][0] = __builtin_amdgcn_mfma_f32_16x16x32_bf16(bb, ax, accP1[p][0], 0, 0, 0);
            accP1[p][1] = __builtin_amdgcn_mfma_f32_16x16x32_bf16(bb, ay, accP1[p][1], 0, 0, 0);
            accP1[p][2] = __builtin_amdgcn_mfma_f32_16x16x32_bf16(bb, az, accP1[p][2], 0, 0, 0);
            accQ[p][0]  = __builtin_amdgcn_mfma_f32_16x16x32_bf16(be, ax, accQ[p][0], 0, 0, 0);
            accQ[p][1]  = __builtin_amdgcn_mfma_f32_16x16x32_bf16(be, ay, accQ[p][1], 0, 0, 0);
            accQ[p][2]  = __builtin_amdgcn_mfma_f32_16x16x32_bf16(be, az, accQ[p][2], 0, 0, 0);
        }
    }

    // ----------------- epilogue: bias, gates, float4 stores -----------------
    // Lane owns node = base+cl; reg j -> output channel o = oo[p] + g4*4 + j.
    const float4 yv = ((const float4*)ysm)[cl];
    const float yy0 = yv.x, y1x = yv.y, y1y = yv.z, y1z = yv.w;
    float* orow = out + (size_t)(base + cl) * 896;
#pragma unroll
    for (int p = 0; p < 2; p++) {
        const int ob = oo[p] + g4 * 4;    // first of 4 consecutive o (mult of 4)
        const float4 bq0 = *(const float4*)(&b0sm[ob]);
        const float4 bq1 = *(const float4*)(&b0sm[128 + ob]);
        const float4 bq2 = *(const float4*)(&b0sm[256 + ob]);
        const float* b0a = (const float*)&bq0;
        const float* b0b = (const float*)&bq1;
        const float* b0c = (const float*)&bq2;
        float feat4[4], vo[12], ve[12];
#pragma unroll
        for (int j = 0; j < 4; j++) {
            float s0 = accS[p][0][j] * INV16 + b0a[j];
            float s1 = accS[p][1][j] * INV16 + b0b[j];
            float s2 = accS[p][2][j] * INV16 + b0c[j];
            float g1o = INV16 / (1.0f + __expf(-s0));   // sigmoid * 1/16 folded
            float g1e = INV16 / (1.0f + __expf(-s1));
            feat4[j] = s2 / (1.0f + __expf(-s2));       // silu
            float P0 = accP0[p][j];
            vo[j * 3 + 0] = (y1x * P0 + yy0 * accP1[p][0][j]) * g1o;
            vo[j * 3 + 1] = (y1y * P0 + yy0 * accP1[p][1][j]) * g1o;
            vo[j * 3 + 2] = (y1z * P0 + yy0 * accP1[p][2][j]) * g1o;
            ve[j * 3 + 0] = (y1z * accQ[p][1][j] - y1y * accQ[p][2][j]) * g1e;
            ve[j * 3 + 1] = (y1x * accQ[p][2][j] - y1z * accQ[p][0][j]) * g1e;
            ve[j * 3 + 2] = (y1y * accQ[p][0][j] - y1x * accQ[p][1][j]) * g1e;
        }
        *(float4*)(orow + ob) = *(const float4*)feat4;            // feats
#pragma unroll
        for (int tq = 0; tq < 3; tq++) {                          // v1o: 12 floats
            *(float4*)(orow + 128 + ob * 3 + tq * 4) = *(const float4*)(vo + tq * 4);
        }
#pragma unroll
        for (int tq = 0; tq < 3; tq++) {                          // v1e: 12 floats
            *(float4*)(orow + 512 + ob * 3 + tq * 4) = *(const float4*)(ve + tq * 4);
        }
    }
}

extern "C" void kernel_launch(void* const* d_in, const int* in_sizes, int n_in,
                              void* d_out, int out_size, void* d_ws, size_t ws_size,
                              hipStream_t stream) {
    (void)in_sizes; (void)n_in; (void)out_size; (void)ws_size;
    const float* x0  = (const float*)d_in[0];
    const float* x1  = (const float*)d_in[1];
    const float* y0  = (const float*)d_in[2];
    const float* y1  = (const float*)d_in[3];
    const float* W0  = (const float*)d_in[4];
    const float* b0  = (const float*)d_in[5];
    const float* W1o = (const float*)d_in[6];
    const float* W1e = (const float*)d_in[7];
    unsigned short* ws = (unsigned short*)d_ws;
    float* out = (float*)d_out;

    prep_w<<<dim3(576), dim3(256), 0, stream>>>(W0, W1o, W1e, ws);
    tpl_gate<<<dim3(65536 / 16), dim3(256), 0, stream>>>(x0, x1, y0, y1, b0, ws, out);
}

// Round 8
// 408.160 us; speedup vs baseline: 1.0989x; 1.0989x over previous
//
#include <hip/hip_runtime.h>
#include <hip/hip_bf16.h>

// ---------------------------------------------------------------------------
// TensorProductLinearGate: fused CG tensor product + block linear + gate.
// N=65536 nodes, MUL=128.
//   s    = tp0 @ W0 /16 + b0            (tp0 = [x0*y0 ; dot(x1,y1)/sqrt3], K=256)
//   v1o  = (y1[i]*p0 + y0*p1[i]) /16    (p0 = x0@W1o_top, p1i = x1i@W1o_bot)
//   v1e  = (y1[i2]*q[i1]-y1[i1]*q[i2])/16   (q_i = x1i@W1e ; /sqrt2/sqrt128 = /16)
//   out  = [silu(s[256:]) | v1o*sig(s[0:128]) | v1e*sig(s[128:256])]
// Round 5-8: 32 nodes/block, 8 waves, o-slice 16/wave, weight fragments
// amortized over 2 node-subtiles, full-line shuffled stores; epilogue LDS
// shuffle race-free (disjoint v1o/v1e regions, barrier-separated phases).
// ---------------------------------------------------------------------------

typedef __bf16 bf16x8 __attribute__((ext_vector_type(8)));
typedef float f32x4 __attribute__((ext_vector_type(4)));
typedef unsigned short u16x8 __attribute__((ext_vector_type(8)));

#define W1OT_TOP 98304
#define W1OT_BOT 114688
#define W1ET     131072
#define INV16 0.0625f
#define INV_SQRT3 0.57735026918962576f

__device__ __forceinline__ unsigned short f2bf(float f) {
    unsigned u = __float_as_uint(f);
    u += 0x7FFFu + ((u >> 16) & 1u);
    return (unsigned short)(u >> 16);
}

// ---- weight prep: f32 [K][out] -> bf16 [out][K] (transposed), into ws ----
__global__ __launch_bounds__(256) void prep_w(const float* __restrict__ W0,
                                              const float* __restrict__ W1o,
                                              const float* __restrict__ W1e,
                                              unsigned short* __restrict__ ws) {
    int idx = blockIdx.x * 256 + threadIdx.x;   // grid covers exactly 147456
    float v;
    if (idx < 98304) {                 // W0T[o][k], o<384, k<256
        int o = idx >> 8, k = idx & 255;
        v = W0[k * 384 + o];
    } else if (idx < 114688) {         // W1o top half: k<128
        int j = idx - 98304; int o = j >> 7, k = j & 127;
        v = W1o[k * 128 + o];
    } else if (idx < 131072) {         // W1o bottom half: k in [128,256)
        int j = idx - 114688; int o = j >> 7, k = j & 127;
        v = W1o[(128 + k) * 128 + o];
    } else {                           // W1e
        int j = idx - 131072; int o = j >> 7, k = j & 127;
        v = W1e[k * 128 + o];
    }
    ws[idx] = f2bf(v);
}

// smraw usage:
//  staging/MFMA phase (as ushort, 49152 B):
//   [0,4096)       x0sm   [32][128]
//   [4096,16384)   x1sm   [3][32][128]
//   [16384,24576)  tp0sm  [32][256]
//   rows XOR-swizzled by ((row&7)*8) on the 8-element-chunk index.
//  epilogue phase (as float, 53248 B):
//   Ro = smf + w*832        (per-wave v1o region, 16 rows x 52 f32)
//   Re = smf + 6656 + w*832 (per-wave v1e region)
__global__ __launch_bounds__(512, 2) void tpl_gate(
    const float* __restrict__ x0, const float* __restrict__ x1,
    const float* __restrict__ y0, const float* __restrict__ y1,
    const float* __restrict__ b0, const unsigned short* __restrict__ ws,
    float* __restrict__ out) {
    __shared__ alignas(16) unsigned char smraw[53248];
    __shared__ alignas(16) float ysm[128];     // [32 nodes][y0,y1x,y1y,y1z]
    __shared__ alignas(16) float b0sm[384];
    unsigned short* sm = (unsigned short*)smraw;
    float* smf = (float*)smraw;

    const int t = threadIdx.x;
    const int base = blockIdx.x * 32;

    // ----------------- staging: global f32 -> LDS bf16 -----------------
    {
        const int r = t >> 4, c0 = (t & 15) * 8;
        const int n = base + r;
        const int swz = (r & 7) * 8;
        const float w0v = y0[n];
        const float w1x = y1[n * 3 + 0], w1y = y1[n * 3 + 1], w1z = y1[n * 3 + 2];

        // x0 chunk + tp0 top (x0*y0)
        const float4* px = (const float4*)(x0 + (size_t)n * 128 + c0);
        float4 a4 = px[0], b4 = px[1];
        float xa[8] = {a4.x, a4.y, a4.z, a4.w, b4.x, b4.y, b4.z, b4.w};
        u16x8 q0, q1;
#pragma unroll
        for (int e = 0; e < 8; e++) { q0[e] = f2bf(xa[e]); q1[e] = f2bf(xa[e] * w0v); }
        *(u16x8*)(&sm[r * 128 + (c0 ^ swz)]) = q0;
        *(u16x8*)(&sm[16384 + r * 256 + (c0 ^ swz)]) = q1;

        // x1 chunk (3 components) + tp0 bottom (dot(x1,y1)/sqrt3)
        const float4* p1 = (const float4*)(x1 + (size_t)n * 384 + c0 * 3);
        float xb[24];
#pragma unroll
        for (int e = 0; e < 6; e++) {
            float4 v = p1[e];
            xb[e * 4 + 0] = v.x; xb[e * 4 + 1] = v.y; xb[e * 4 + 2] = v.z; xb[e * 4 + 3] = v.w;
        }
        u16x8 qx, qy, qz, qt;
#pragma unroll
        for (int e = 0; e < 8; e++) {
            float vx = xb[e * 3 + 0], vy = xb[e * 3 + 1], vz = xb[e * 3 + 2];
            qx[e] = f2bf(vx); qy[e] = f2bf(vy); qz[e] = f2bf(vz);
            qt[e] = f2bf((vx * w1x + vy * w1y + vz * w1z) * INV_SQRT3);
        }
        *(u16x8*)(&sm[4096  + r * 128 + (c0 ^ swz)]) = qx;
        *(u16x8*)(&sm[8192  + r * 128 + (c0 ^ swz)]) = qy;
        *(u16x8*)(&sm[12288 + r * 128 + (c0 ^ swz)]) = qz;
        *(u16x8*)(&sm[16384 + r * 256 + ((128 + c0) ^ swz)]) = qt;

        if (t < 32) {
            int nn = base + t;
            ysm[t * 4 + 0] = y0[nn];
            ysm[t * 4 + 1] = y1[nn * 3 + 0];
            ysm[t * 4 + 2] = y1[nn * 3 + 1];
            ysm[t * 4 + 3] = y1[nn * 3 + 2];
        }
        if (t < 96) ((float4*)b0sm)[t] = ((const float4*)b0)[t];
    }
    __syncthreads();

    // ----------------- MFMA phase (swapped operands: D[o][node]) -----------------
    const int w = t >> 6, lane = t & 63;
    const int cl = lane & 15, g4 = lane >> 4;
    const int swzr = (cl & 7) * 8;
    const int ob = w * 16;             // this wave's o-slice [ob, ob+16)

    f32x4 accS[2][3], accP0[2], accP1[2][3], accQ[2][3];   // [node-subtile][...]
#pragma unroll
    for (int n = 0; n < 2; n++) {
        accP0[n] = (f32x4)(0.0f);
#pragma unroll
        for (int g = 0; g < 3; g++) accS[n][g] = (f32x4)(0.0f);
#pragma unroll
        for (int i = 0; i < 3; i++) { accP1[n][i] = (f32x4)(0.0f); accQ[n][i] = (f32x4)(0.0f); }
    }

    // s-path: tp0 (K=256) x W0T rows {g*128+ob+cl}
#pragma unroll
    for (int ks = 0; ks < 8; ks++) {
        const int eb = ks * 32 + g4 * 8;
        bf16x8 bw[3];
#pragma unroll
        for (int g = 0; g < 3; g++)
            bw[g] = *(const bf16x8*)(&ws[(g * 128 + ob + cl) * 256 + eb]);
#pragma unroll
        for (int n = 0; n < 2; n++) {
            bf16x8 a = *(const bf16x8*)(&sm[16384 + (16 * n + cl) * 256 + (eb ^ swzr)]);
#pragma unroll
            for (int g = 0; g < 3; g++)
                accS[n][g] = __builtin_amdgcn_mfma_f32_16x16x32_bf16(bw[g], a, accS[n][g], 0, 0, 0);
        }
    }
    // v-path: x0/x1 (K=128) x {W1o_top, W1o_bot, W1e} rows {ob+cl}
#pragma unroll
    for (int k = 0; k < 4; k++) {
        const int eb = k * 32 + g4 * 8;
        bf16x8 bt = *(const bf16x8*)(&ws[W1OT_TOP + (ob + cl) * 128 + eb]);
        bf16x8 bb = *(const bf16x8*)(&ws[W1OT_BOT + (ob + cl) * 128 + eb]);
        bf16x8 be = *(const bf16x8*)(&ws[W1ET     + (ob + cl) * 128 + eb]);
#pragma unroll
        for (int n = 0; n < 2; n++) {
            const int nr = 16 * n + cl;
            bf16x8 a0 = *(const bf16x8*)(&sm[        nr * 128 + (eb ^ swzr)]);
            bf16x8 ax = *(const bf16x8*)(&sm[4096  + nr * 128 + (eb ^ swzr)]);
            bf16x8 ay = *(const bf16x8*)(&sm[8192  + nr * 128 + (eb ^ swzr)]);
            bf16x8 az = *(const bf16x8*)(&sm[12288 + nr * 128 + (eb ^ swzr)]);
            accP0[n]    = __builtin_amdgcn_mfma_f32_16x16x32_bf16(bt, a0, accP0[n], 0, 0, 0);
            accP1[n][0] = __builtin_amdgcn_mfma_f32_16x16x32_bf16(bb, ax, accP1[n][0], 0, 0, 0);
            accP1[n][1] = __builtin_amdgcn_mfma_f32_16x16x32_bf16(bb, ay, accP1[n][1], 0, 0, 0);
            accP1[n][2] = __builtin_amdgcn_mfma_f32_16x16x32_bf16(bb, az, accP1[n][2], 0, 0, 0);
            accQ[n][0]  = __builtin_amdgcn_mfma_f32_16x16x32_bf16(be, ax, accQ[n][0], 0, 0, 0);
            accQ[n][1]  = __builtin_amdgcn_mfma_f32_16x16x32_bf16(be, ay, accQ[n][1], 0, 0, 0);
            accQ[n][2]  = __builtin_amdgcn_mfma_f32_16x16x32_bf16(be, az, accQ[n][2], 0, 0, 0);
        }
    }

    __syncthreads();   // all waves done reading sm -> safe to reuse as f32 space

    // ----------------- epilogue -----------------
    // Lane holds, for node = 16n+cl and o = ob+g4*4+j, the 10 output groups.
    // feat stores are full-line direct; v1o/v1e go through per-wave LDS regions
    // (DISJOINT; barrier-separated write->read) so every global store
    // instruction writes full 64B lines.
    float* Ro = smf + w * 832;          // v1o region: 16 rows x 52 f32
    float* Re = smf + 6656 + w * 832;   // v1e region

#pragma unroll
    for (int n = 0; n < 2; n++) {
        const int node = 16 * n + cl;
        const float4 yv = ((const float4*)ysm)[node];
        const float yy0 = yv.x, y1x = yv.y, y1y = yv.z, y1z = yv.w;
        const int o4 = ob + g4 * 4;
        const float4 bq0 = *(const float4*)(&b0sm[o4]);
        const float4 bq1 = *(const float4*)(&b0sm[128 + o4]);
        const float4 bq2 = *(const float4*)(&b0sm[256 + o4]);
        const float* b0a = (const float*)&bq0;
        const float* b0b = (const float*)&bq1;
        const float* b0c = (const float*)&bq2;
        float4 featq, vo4[3], ve4[3];
        float* feat4 = (float*)&featq;
        float* vo = (float*)vo4;
        float* ve = (float*)ve4;
#pragma unroll
        for (int j = 0; j < 4; j++) {
            float s0 = accS[n][0][j] * INV16 + b0a[j];
            float s1 = accS[n][1][j] * INV16 + b0b[j];
            float s2 = accS[n][2][j] * INV16 + b0c[j];
            float g1o = INV16 / (1.0f + __expf(-s0));   // sigmoid * 1/16 folded
            float g1e = INV16 / (1.0f + __expf(-s1));
            feat4[j] = s2 / (1.0f + __expf(-s2));       // silu
            float P0 = accP0[n][j];
            vo[j * 3 + 0] = (y1x * P0 + yy0 * accP1[n][0][j]) * g1o;
            vo[j * 3 + 1] = (y1y * P0 + yy0 * accP1[n][1][j]) * g1o;
            vo[j * 3 + 2] = (y1z * P0 + yy0 * accP1[n][2][j]) * g1o;
            ve[j * 3 + 0] = (y1z * accQ[n][1][j] - y1y * accQ[n][2][j]) * g1e;
            ve[j * 3 + 1] = (y1x * accQ[n][2][j] - y1z * accQ[n][0][j]) * g1e;
            ve[j * 3 + 2] = (y1y * accQ[n][0][j] - y1x * accQ[n][1][j]) * g1e;
        }
        // feat: wave's 64B region per node, full lines
        *(float4*)(out + (size_t)(base + node) * 896 + o4) = featq;

        // write phase: lane's 12 v1o floats -> Ro row cl, 12 v1e floats -> Re
        {
            float* wo = Ro + cl * 52 + g4 * 12;
            float* we = Re + cl * 52 + g4 * 12;
            ((float4*)wo)[0] = vo4[0];
            ((float4*)wo)[1] = vo4[1];
            ((float4*)wo)[2] = vo4[2];
            ((float4*)we)[0] = ve4[0];
            ((float4*)we)[1] = ve4[1];
            ((float4*)we)[2] = ve4[2];
        }
        __syncthreads();   // writes visible before lane-contiguous reads

        // read phase: 192 16B pieces per region; consecutive lanes ->
        // consecutive global addresses -> full 64B lines.
#pragma unroll
        for (int m = 0; m < 3; m++) {
            int piece = m * 64 + lane;          // 192 pieces of 16B
            int nd = (int)((unsigned)piece / 12u);  // node within subtile
            int kk = piece - nd * 12;           // 16B piece within node slice
            float4 v = *(const float4*)(Ro + nd * 52 + kk * 4);
            *(float4*)(out + (size_t)(base + 16 * n + nd) * 896 + 128 + w * 48 + kk * 4) = v;
        }
#pragma unroll
        for (int m = 0; m < 3; m++) {
            int piece = m * 64 + lane;
            int nd = (int)((unsigned)piece / 12u);
            int kk = piece - nd * 12;
            float4 v = *(const float4*)(Re + nd * 52 + kk * 4);
            *(float4*)(out + (size_t)(base + 16 * n + nd) * 896 + 512 + w * 48 + kk * 4) = v;
        }
        __syncthreads();   // reads done before next n overwrites regions
    }
}

extern "C" void kernel_launch(void* const* d_in, const int* in_sizes, int n_in,
                              void* d_out, int out_size, void* d_ws, size_t ws_size,
                              hipStream_t stream) {
    (void)in_sizes; (void)n_in; (void)out_size; (void)ws_size;
    const float* x0  = (const float*)d_in[0];
    const float* x1  = (const float*)d_in[1];
    const float* y0  = (const float*)d_in[2];
    const float* y1  = (const float*)d_in[3];
    const float* W0  = (const float*)d_in[4];
    const float* b0  = (const float*)d_in[5];
    const float* W1o = (const float*)d_in[6];
    const float* W1e = (const float*)d_in[7];
    unsigned short* ws = (unsigned short*)d_ws;
    float* out = (float*)d_out;

    prep_w<<<dim3(576), dim3(256), 0, stream>>>(W0, W1o, W1e, ws);
    tpl_gate<<<dim3(65536 / 32), dim3(512), 0, stream>>>(x0, x1, y0, y1, b0, ws, out);
}